// Round 4
// baseline (301.280 us; speedup 1.0000x reference)
//
#include <hip/hip_runtime.h>
#include <hip/hip_bf16.h>

// SlotContrastiveLoss B=32768, K=8, D=256 fp32.
// R4: dense coalesced global_load_lds staging (K-stage=64 floats, 8KB/wave),
// XOR-swizzled LDS (linear DMA dest + inverse-swizzled global src + swizzled
// ds_read_b128, rule #21), validated R2 MFMA math (absmax 0.0), fused final
// reduction via device-scope atomics + counter (deterministic fixed-order sum).

typedef __attribute__((ext_vector_type(8))) short bf16x8;
typedef __attribute__((ext_vector_type(4))) float f32x4;

union BFPack { bf16x8 v; __hip_bfloat162 h[4]; };

__device__ inline bf16x8 pack8(const float4& lo, const float4& hi) {
  BFPack u;
  u.h[0] = __float22bfloat162_rn(make_float2(lo.x, lo.y));
  u.h[1] = __float22bfloat162_rn(make_float2(lo.z, lo.w));
  u.h[2] = __float22bfloat162_rn(make_float2(hi.x, hi.y));
  u.h[3] = __float22bfloat162_rn(make_float2(hi.z, hi.w));
  return u.v;
}

#define GLL16(gaddr, laddr)                                                    \
  __builtin_amdgcn_global_load_lds(                                            \
      (const __attribute__((address_space(1))) void*)(gaddr),                  \
      (__attribute__((address_space(3))) void*)(laddr), 16, 0, 0)

extern "C" __global__ __launch_bounds__(256, 5)
void slot_ce_fused(const float* __restrict__ ds, const float* __restrict__ ss,
                   const float* __restrict__ tptr, float* __restrict__ ws,
                   unsigned* __restrict__ counter, float* __restrict__ out,
                   int ntiles, int nblocks, float scale) {
  __shared__ char lds[32768];                 // 4 waves x [A 4KB | S 4KB]
  const int tid  = threadIdx.x;
  const int lane = tid & 63;
  const int wv   = tid >> 6;
  const int wid  = blockIdx.x * 4 + wv;
  const int m  = lane & 15;                   // fragment row / C col
  const int h  = lane >> 4;                   // k-slice group / C row group
  const float inv_t = 1.0f / tptr[0];

  char* wreg = &lds[wv * 8192];
  float loss = 0.0f;

  if (wid < ntiles) {
    const char* gA = (const char*)ds + (size_t)wid * 16384;  // 2 batches = 16KB
    const char* gB = (const char*)ss + (size_t)wid * 16384;

    // DMA instr j fills LDS rows j*4..j*4+3 linearly (lane*16). Lane's global
    // source slot is inverse-swizzled: LDS[r][p] = global[r][p ^ (r&7)].
    int srcoff[4];
#pragma unroll
    for (int j = 0; j < 4; ++j) {
      const int row = j * 4 + (lane >> 4);
      srcoff[j] = row * 1024 + ((m ^ (row & 7)) << 4);
    }

    f32x4 acc = {0.f, 0.f, 0.f, 0.f};
    float ssqA = 0.f, ssqS = 0.f;

#pragma unroll
    for (int ks = 0; ks < 4; ++ks) {          // K-stage: 64 floats (256B/row)
      const int kofs = ks * 256;
#pragma unroll
      for (int j = 0; j < 4; ++j) GLL16(gA + srcoff[j] + kofs, wreg + j * 1024);
#pragma unroll
      for (int j = 0; j < 4; ++j) GLL16(gB + srcoff[j] + kofs, wreg + 4096 + j * 1024);
      asm volatile("s_waitcnt vmcnt(0)" ::: "memory");

#pragma unroll
      for (int kb = 0; kb < 2; ++kb) {        // two K=32 MFMA chunks per stage
        const int sbase = kb * 8 + h * 2;
        const int swz = m & 7;
        const float4 a0 = *(const float4*)(wreg +        m * 256 + (((sbase + 0) ^ swz) << 4));
        const float4 a1 = *(const float4*)(wreg +        m * 256 + (((sbase + 1) ^ swz) << 4));
        const float4 s0 = *(const float4*)(wreg + 4096 + m * 256 + (((sbase + 0) ^ swz) << 4));
        const float4 s1 = *(const float4*)(wreg + 4096 + m * 256 + (((sbase + 1) ^ swz) << 4));

        ssqA += a0.x*a0.x + a0.y*a0.y + a0.z*a0.z + a0.w*a0.w
              + a1.x*a1.x + a1.y*a1.y + a1.z*a1.z + a1.w*a1.w;
        ssqS += s0.x*s0.x + s0.y*s0.y + s0.z*s0.z + s0.w*s0.w
              + s1.x*s1.x + s1.y*s1.y + s1.z*s1.z + s1.w*s1.w;

        acc = __builtin_amdgcn_mfma_f32_16x16x32_bf16(
            pack8(a0, a1), pack8(s0, s1), acc, 0, 0, 0);
      }
      if (ks < 3) asm volatile("s_waitcnt lgkmcnt(0)" ::: "memory");  // reads done before overwrite
    }

    // ---- epilogue: identical to validated R2/R3 math ----
    ssqA += __shfl_xor(ssqA, 16, 64);
    ssqA += __shfl_xor(ssqA, 32, 64);
    ssqS += __shfl_xor(ssqS, 16, 64);
    ssqS += __shfl_xor(ssqS, 32, 64);
    float na0 = __shfl(ssqA, h * 4 + 0, 64);
    float na1 = __shfl(ssqA, h * 4 + 1, 64);
    float na2 = __shfl(ssqA, h * 4 + 2, 64);
    float na3 = __shfl(ssqA, h * 4 + 3, 64);

    float lg0 = acc[0] * rsqrtf(na0 * ssqS) * inv_t;
    float lg1 = acc[1] * rsqrtf(na1 * ssqS) * inv_t;
    float lg2 = acc[2] * rsqrtf(na2 * ssqS) * inv_t;
    float lg3 = acc[3] * rsqrtf(na3 * ssqS) * inv_t;

    float c = 0.0f;
#pragma unroll
    for (int r = 0; r < 4; ++r) {
      float lg = r == 0 ? lg0 : r == 1 ? lg1 : r == 2 ? lg2 : lg3;
      float mx = lg;
      mx = fmaxf(mx, __shfl_xor(mx, 1, 64));
      mx = fmaxf(mx, __shfl_xor(mx, 2, 64));
      mx = fmaxf(mx, __shfl_xor(mx, 4, 64));
      float e = __expf(lg - mx);
      e += __shfl_xor(e, 1, 64);
      e += __shfl_xor(e, 2, 64);
      e += __shfl_xor(e, 4, 64);
      float lse = mx + __logf(e);
      c += lse * 0.125f;
      if (4 * h + r == m) c -= lg;
    }
    if ((m >= 8) == (h >= 2)) loss = c;
  }

  // ---- block reduction (reuse LDS; all stage DMA/reads drained per-wave) ----
#pragma unroll
  for (int o = 32; o >= 1; o >>= 1) loss += __shfl_xor(loss, o, 64);
  float* redp = (float*)lds;
  __syncthreads();
  if (lane == 0) redp[wv] = loss;
  __syncthreads();
  if (tid == 0) {
    const float part = (redp[0] + redp[1]) + (redp[2] + redp[3]);
    atomicExch(&ws[blockIdx.x], part);        // device-coherent write
    __threadfence();
    unsigned old = atomicAdd(counter, 1u);
    *(unsigned*)(lds + 16) = (old == (unsigned)(nblocks - 1)) ? 1u : 0u;
  }
  __syncthreads();
  const bool last = *(volatile unsigned*)(lds + 16) != 0u;
  __syncthreads();                            // everyone sampled the flag

  if (last) {                                 // block-uniform
    __threadfence();
    float s = 0.0f;
    for (int i = tid; i < nblocks; i += 256) s += ws[i];   // fixed order
    ((float*)lds)[tid] = s;
    __syncthreads();
    for (int o = 128; o >= 1; o >>= 1) {
      if (tid < o) ((float*)lds)[tid] += ((float*)lds)[tid + o];
      __syncthreads();
    }
    if (tid == 0) out[0] = ((float*)lds)[0] * scale;
  }
}

extern "C" void kernel_launch(void* const* d_in, const int* in_sizes, int n_in,
                              void* d_out, int out_size, void* d_ws, size_t ws_size,
                              hipStream_t stream) {
  const float* ds   = (const float*)d_in[0];
  const float* ss   = (const float*)d_in[1];
  const float* tptr = (const float*)d_in[3];   // d_in[2] = labels (unused)
  float* out = (float*)d_out;
  float* ws  = (float*)d_ws;                   // [0,16384): partials
  unsigned* counter = (unsigned*)((char*)d_ws + 16384);

  const int B       = in_sizes[0] / (8 * 256); // 32768
  const int ntiles  = B / 2;                   // 16384
  const int nblocks = (ntiles + 3) / 4;        // 4096

  hipMemsetAsync(counter, 0, sizeof(unsigned), stream);
  const float scale = 1.0f / (8.0f * (float)B);
  slot_ce_fused<<<nblocks, 256, 0, stream>>>(ds, ss, tptr, ws, counter, out,
                                             ntiles, nblocks, scale);
}

// Round 5
// 100.740 us; speedup vs baseline: 2.9907x; 2.9907x over previous
//
#include <hip/hip_runtime.h>
#include <hip/hip_bf16.h>

// SlotContrastiveLoss B=32768, K=8, D=256 fp32.
// R5: revert to validated R2 structure (absmax 0.0). Single change: permute
// the MFMA k-dim (= D, legal if applied to BOTH operands) so each lane's two
// float4 fragment loads sit at slots {h, h+4} of the 128B k-chunk instead of
// {2h, 2h+1}. Per load instruction the wave then touches 16 x 64B contiguous
// runs (one per row) instead of 64 x 16B gapped pieces -> half the TA sector
// requests, R1-dense-level coalescing, no LDS / no shfl redistribution.
// C-layout col=lane&15, row=(lane>>4)*4+reg (m89-verified, R2-validated).

typedef __attribute__((ext_vector_type(8))) short bf16x8;
typedef __attribute__((ext_vector_type(4))) float f32x4;

union BFPack { bf16x8 v; __hip_bfloat162 h[4]; };

__device__ inline bf16x8 pack8(const float4& lo, const float4& hi) {
  BFPack u;
  u.h[0] = __float22bfloat162_rn(make_float2(lo.x, lo.y));
  u.h[1] = __float22bfloat162_rn(make_float2(lo.z, lo.w));
  u.h[2] = __float22bfloat162_rn(make_float2(hi.x, hi.y));
  u.h[3] = __float22bfloat162_rn(make_float2(hi.z, hi.w));
  return u.v;
}

extern "C" __global__ __launch_bounds__(256)
void slot_ce_mfma(const float* __restrict__ ds, const float* __restrict__ ss,
                  const float* __restrict__ tptr, float* __restrict__ ws,
                  int ntiles) {
  const int lane = threadIdx.x & 63;
  const int wid  = blockIdx.x * 4 + (threadIdx.x >> 6);
  const int m = lane & 15;            // fragment row / C col
  const int h = lane >> 4;            // k-slice group / C row group
  const float inv_t = 1.0f / tptr[0];

  float loss = 0.0f;

  if (wid < ntiles) {
    const float4* pa = (const float4*)(ds + (size_t)wid * 4096);
    const float4* pb = (const float4*)(ss + (size_t)wid * 4096);
    // k-permuted fragment slots: {h, h+4} of each 8-float4 k-chunk.
    // Instruction footprint: rows m=0..15, bytes [h*16, h*16+16) -> 64B runs.
    const int base = m * 64 + h;

    f32x4 acc = {0.f, 0.f, 0.f, 0.f};
    float ssqA = 0.f, ssqS = 0.f;

#pragma unroll
    for (int kb = 0; kb < 8; ++kb) {
      const int i0 = base + kb * 8;
      float4 a0 = pa[i0], a1 = pa[i0 + 4];
      float4 s0 = pb[i0], s1 = pb[i0 + 4];

      ssqA += a0.x*a0.x + a0.y*a0.y + a0.z*a0.z + a0.w*a0.w
            + a1.x*a1.x + a1.y*a1.y + a1.z*a1.z + a1.w*a1.w;
      ssqS += s0.x*s0.x + s0.y*s0.y + s0.z*s0.z + s0.w*s0.w
            + s1.x*s1.x + s1.y*s1.y + s1.z*s1.z + s1.w*s1.w;

      acc = __builtin_amdgcn_mfma_f32_16x16x32_bf16(
          pack8(a0, a1), pack8(s0, s1), acc, 0, 0, 0);
    }

    // fold ssq over the 4 lanes sharing row m (bits 4,5)
    ssqA += __shfl_xor(ssqA, 16, 64);
    ssqA += __shfl_xor(ssqA, 32, 64);
    ssqS += __shfl_xor(ssqS, 16, 64);
    ssqS += __shfl_xor(ssqS, 32, 64);
    // C col = m, so ssqS is already this lane's col norm^2.
    float na0 = __shfl(ssqA, h * 4 + 0, 64);
    float na1 = __shfl(ssqA, h * 4 + 1, 64);
    float na2 = __shfl(ssqA, h * 4 + 2, 64);
    float na3 = __shfl(ssqA, h * 4 + 3, 64);

    float lg0 = acc[0] * rsqrtf(na0 * ssqS) * inv_t;
    float lg1 = acc[1] * rsqrtf(na1 * ssqS) * inv_t;
    float lg2 = acc[2] * rsqrtf(na2 * ssqS) * inv_t;
    float lg3 = acc[3] * rsqrtf(na3 * ssqS) * inv_t;

    float c = 0.0f;
#pragma unroll
    for (int r = 0; r < 4; ++r) {
      float lg = r == 0 ? lg0 : r == 1 ? lg1 : r == 2 ? lg2 : lg3;
      float mx = lg;
      mx = fmaxf(mx, __shfl_xor(mx, 1, 64));
      mx = fmaxf(mx, __shfl_xor(mx, 2, 64));
      mx = fmaxf(mx, __shfl_xor(mx, 4, 64));
      float e = __expf(lg - mx);
      e += __shfl_xor(e, 1, 64);
      e += __shfl_xor(e, 2, 64);
      e += __shfl_xor(e, 4, 64);
      float lse = mx + __logf(e);
      c += lse * 0.125f;                 // lse replicated across 8 col-lanes
      if (4 * h + r == m) c -= lg;       // diagonal positive
    }
    if ((m >= 8) == (h >= 2)) loss = c;  // same-batch quadrants only
  }

  // deterministic wave -> block reduction
#pragma unroll
  for (int o = 32; o >= 1; o >>= 1) loss += __shfl_xor(loss, o, 64);
  __shared__ float red[4];
  if (lane == 0) red[threadIdx.x >> 6] = loss;
  __syncthreads();
  if (threadIdx.x == 0)
    ws[blockIdx.x] = (red[0] + red[1]) + (red[2] + red[3]);
}

extern "C" __global__ __launch_bounds__(256)
void slot_ce_finish(const float* __restrict__ ws, float* __restrict__ out,
                    int nparts, float scale) {
  __shared__ float red[256];
  float s = 0.0f;
  for (int i = threadIdx.x; i < nparts; i += 256) s += ws[i];
  red[threadIdx.x] = s;
  __syncthreads();
  for (int o = 128; o >= 1; o >>= 1) {
    if ((int)threadIdx.x < o) red[threadIdx.x] += red[threadIdx.x + o];
    __syncthreads();
  }
  if (threadIdx.x == 0) out[0] = red[0] * scale;
}

extern "C" void kernel_launch(void* const* d_in, const int* in_sizes, int n_in,
                              void* d_out, int out_size, void* d_ws, size_t ws_size,
                              hipStream_t stream) {
  const float* ds   = (const float*)d_in[0];
  const float* ss   = (const float*)d_in[1];
  const float* tptr = (const float*)d_in[3];   // d_in[2] = labels (unused)
  float* out = (float*)d_out;
  float* ws  = (float*)d_ws;

  const int B      = in_sizes[0] / (8 * 256);  // 32768
  const int ntiles = B / 2;                    // 2 batches per wave-tile
  const int blocks = (ntiles + 3) / 4;         // 4 waves per block -> 4096

  slot_ce_mfma<<<blocks, 256, 0, stream>>>(ds, ss, tptr, ws, ntiles);
  const float scale = 1.0f / (8.0f * (float)B);
  slot_ce_finish<<<1, 256, 0, stream>>>(ws, out, blocks, scale);
}